// Round 5
// baseline (239.582 us; speedup 1.0000x reference)
//
#include <hip/hip_runtime.h>

#define BB 8
#define CC 64
#define UU 3
#define NN 512
#define POS (UU * NN)               // 1536
#define QKV_ELEMS (BB * CC * POS)   // 786432 floats per tensor
// 0.125 (= C^-0.5) * log2(e), folded into q so softmax uses raw exp2
#define SCALE2 0.1803368801111793f

// ---------------- Kernel 1: projection (round-3 proven version) ------------
// grid = BB*32*6 = 1536 blocks; each block: one b, TWO output channels d0,d0+1,
// 256 positions. x loads are coalesced and reused across both channels.
__global__ __launch_bounds__(256) void proj_kernel(
    const float* __restrict__ x,
    const float* __restrict__ Wq,
    const float* __restrict__ Wk,
    const float* __restrict__ Wv,
    float* __restrict__ ws)
{
    const int blk   = blockIdx.x;        // 0..1535
    const int bd2   = blk / 6;           // 0..255 : (b, d-pair)
    const int chunk = blk % 6;
    const int b     = bd2 >> 5;
    const int d0    = (bd2 & 31) * 2;
    const int tid   = threadIdx.x;
    const int p     = chunk * 256 + tid; // 0..1535

    __shared__ float w[6][CC];           // rows: q_d0,q_d1,k_d0,k_d1,v_d0,v_d1
    if (tid < 128) {
        int r = tid >> 6, c = tid & 63;
        w[r][c]     = Wq[(d0 + r) * CC + c];
        w[2 + r][c] = Wk[(d0 + r) * CC + c];
        w[4 + r][c] = Wv[(d0 + r) * CC + c];
    }
    __syncthreads();

    const float* xb = x + (size_t)b * CC * POS + p;
    float q0 = 0.f, q1 = 0.f, k0 = 0.f, k1 = 0.f, v0 = 0.f, v1 = 0.f;
    #pragma unroll 8
    for (int c = 0; c < CC; ++c) {
        float xv = xb[c * POS];
        q0 = fmaf(xv, w[0][c], q0);
        q1 = fmaf(xv, w[1][c], q1);
        k0 = fmaf(xv, w[2][c], k0);
        k1 = fmaf(xv, w[3][c], k1);
        v0 = fmaf(xv, w[4][c], v0);
        v1 = fmaf(xv, w[5][c], v1);
    }

    float* qs = ws;
    float* ks = ws + QKV_ELEMS;
    float* vs = ws + 2 * QKV_ELEMS;
    size_t base = (size_t)(b * CC + d0) * POS + p;
    qs[base] = q0 * SCALE2;  qs[base + POS] = q1 * SCALE2;
    ks[base] = k0;           ks[base + POS] = k1;
    vs[base] = v0;           vs[base + POS] = v1;
}

// ---------------- Kernel 2: attention, split-j (2 lanes per row) -----------
// Softmax without max-subtraction is a pure sum -> j-splittable. Lane pair
// (2r, 2r+1) handles row r: lane h sums j in [h*256, h*256+256), then one
// shfl_xor(1) combines l/a0/a1/a2. K/V loads are per-lane vector loads
// (2 distinct float4 addrs per wave, L1-resident). No LDS, no scalar loads.
// grid = 512 bd * 4 row-quarters = 2048 blocks -> 8 blocks/CU.
__global__ __launch_bounds__(256) void attn_kernel(
    const float* __restrict__ x,
    const float* __restrict__ ws,
    float* __restrict__ out)
{
    const int blk = blockIdx.x;        // 0..2047
    const int bd  = blk >> 2;          // 0..511
    const int qb  = blk & 3;           // row quarter
    const int tid = threadIdx.x;
    const int i   = qb * 128 + (tid >> 1);  // row 0..511
    const int h   = tid & 1;                // j-half

    const float* qsg = ws + (size_t)bd * POS;
    const float* ksg = ws + QKV_ELEMS     + (size_t)bd * POS;
    const float* vsg = ws + 2 * QKV_ELEMS + (size_t)bd * POS;

    const float q0 = qsg[i];            // already * C^-0.5 * log2(e)
    const float q1 = qsg[NN + i];
    const float q2 = qsg[2 * NN + i];

    const float4* k0p = (const float4*)ksg            + h * 64;
    const float4* k1p = (const float4*)(ksg + NN)     + h * 64;
    const float4* k2p = (const float4*)(ksg + 2 * NN) + h * 64;
    const float4* v0p = (const float4*)vsg            + h * 64;
    const float4* v1p = (const float4*)(vsg + NN)     + h * 64;
    const float4* v2p = (const float4*)(vsg + 2 * NN) + h * 64;

    float l = 0.f, a0 = 0.f, a1 = 0.f, a2 = 0.f;
    #pragma unroll 2
    for (int t = 0; t < 64; ++t) {
        float4 k0 = k0p[t];
        float4 k1 = k1p[t];
        float4 k2 = k2p[t];
        float4 v0 = v0p[t];
        float4 v1 = v1p[t];
        float4 v2 = v2p[t];

        float s0 = fmaf(q0, k0.x, fmaf(q1, k1.x, q2 * k2.x));
        float s1 = fmaf(q0, k0.y, fmaf(q1, k1.y, q2 * k2.y));
        float s2 = fmaf(q0, k0.z, fmaf(q1, k1.z, q2 * k2.z));
        float s3 = fmaf(q0, k0.w, fmaf(q1, k1.w, q2 * k2.w));

        float p0 = __builtin_amdgcn_exp2f(s0);
        float p1 = __builtin_amdgcn_exp2f(s1);
        float p2 = __builtin_amdgcn_exp2f(s2);
        float p3 = __builtin_amdgcn_exp2f(s3);

        l += (p0 + p1) + (p2 + p3);
        a0 = fmaf(p0, v0.x, fmaf(p1, v0.y, fmaf(p2, v0.z, fmaf(p3, v0.w, a0))));
        a1 = fmaf(p0, v1.x, fmaf(p1, v1.y, fmaf(p2, v1.z, fmaf(p3, v1.w, a1))));
        a2 = fmaf(p0, v2.x, fmaf(p1, v2.y, fmaf(p2, v2.z, fmaf(p3, v2.w, a2))));
    }

    // combine the two j-halves of this row (within-wave pair)
    l  += __shfl_xor(l,  1);
    a0 += __shfl_xor(a0, 1);
    a1 += __shfl_xor(a1, 1);
    a2 += __shfl_xor(a2, 1);

    if (h == 0) {
        float inv = 1.0f / l;
        const float* xd = x   + (size_t)bd * POS;
        float*       od = out + (size_t)bd * POS;
        od[i]          = xd[i]          + a0 * inv;
        od[NN + i]     = xd[NN + i]     + a1 * inv;
        od[2 * NN + i] = xd[2 * NN + i] + a2 * inv;
    }
}

// ---------------- Fallback: fused kernel (if ws too small) -----------------
__global__ __launch_bounds__(256) void vn_attn_fused(
    const float* __restrict__ x,
    const float* __restrict__ Wq,
    const float* __restrict__ Wk,
    const float* __restrict__ Wv,
    float* __restrict__ out)
{
    const int bd  = blockIdx.x;
    const int b   = bd / CC;
    const int d   = bd % CC;
    const int tid = threadIdx.x;

    __shared__ float wq[CC], wk[CC], wv[CC];
    __shared__ float qs[UU][NN];
    __shared__ float ks[UU][NN];
    __shared__ float vs[UU][NN];

    if (tid < CC) {
        wq[tid] = Wq[d * CC + tid];
        wk[tid] = Wk[d * CC + tid];
        wv[tid] = Wv[d * CC + tid];
    }
    __syncthreads();

    const float* xb = x + (size_t)b * CC * POS;
    for (int p = tid; p < POS; p += 256) {
        float qa = 0.f, ka = 0.f, va = 0.f;
        #pragma unroll 8
        for (int c = 0; c < CC; ++c) {
            float xv = xb[c * POS + p];
            qa = fmaf(xv, wq[c], qa);
            ka = fmaf(xv, wk[c], ka);
            va = fmaf(xv, wv[c], va);
        }
        int u = p >> 9, n = p & (NN - 1);
        qs[u][n] = qa * SCALE2;
        ks[u][n] = ka;
        vs[u][n] = va;
    }
    __syncthreads();

    for (int i = tid; i < NN; i += 256) {
        float q0 = qs[0][i], q1 = qs[1][i], q2 = qs[2][i];
        float l = 0.f, a0 = 0.f, a1 = 0.f, a2 = 0.f;
        for (int j = 0; j < NN; j += 4) {
            float4 k0 = *(const float4*)&ks[0][j];
            float4 k1 = *(const float4*)&ks[1][j];
            float4 k2 = *(const float4*)&ks[2][j];
            float4 v0 = *(const float4*)&vs[0][j];
            float4 v1 = *(const float4*)&vs[1][j];
            float4 v2 = *(const float4*)&vs[2][j];
            float s0 = fmaf(q0, k0.x, fmaf(q1, k1.x, q2 * k2.x));
            float s1 = fmaf(q0, k0.y, fmaf(q1, k1.y, q2 * k2.y));
            float s2 = fmaf(q0, k0.z, fmaf(q1, k1.z, q2 * k2.z));
            float s3 = fmaf(q0, k0.w, fmaf(q1, k1.w, q2 * k2.w));
            float p0 = __builtin_amdgcn_exp2f(s0);
            float p1 = __builtin_amdgcn_exp2f(s1);
            float p2 = __builtin_amdgcn_exp2f(s2);
            float p3 = __builtin_amdgcn_exp2f(s3);
            l += p0 + p1 + p2 + p3;
            a0 = fmaf(p0, v0.x, fmaf(p1, v0.y, fmaf(p2, v0.z, fmaf(p3, v0.w, a0))));
            a1 = fmaf(p0, v1.x, fmaf(p1, v1.y, fmaf(p2, v1.z, fmaf(p3, v1.w, a1))));
            a2 = fmaf(p0, v2.x, fmaf(p1, v2.y, fmaf(p2, v2.z, fmaf(p3, v2.w, a2))));
        }
        float inv = 1.0f / l;
        size_t obase = ((size_t)(b * CC + d) * UU) * NN + i;
        const float* xd = xb + (size_t)d * POS;
        out[obase]          = xd[i]          + a0 * inv;
        out[obase + NN]     = xd[NN + i]     + a1 * inv;
        out[obase + 2 * NN] = xd[2 * NN + i] + a2 * inv;
    }
}

extern "C" void kernel_launch(void* const* d_in, const int* in_sizes, int n_in,
                              void* d_out, int out_size, void* d_ws, size_t ws_size,
                              hipStream_t stream) {
    const float* x  = (const float*)d_in[0];
    const float* Wq = (const float*)d_in[1];
    const float* Wk = (const float*)d_in[2];
    const float* Wv = (const float*)d_in[3];
    float* out = (float*)d_out;

    if (ws_size >= (size_t)3 * QKV_ELEMS * sizeof(float)) {
        float* ws = (float*)d_ws;
        proj_kernel<<<dim3(BB * 32 * 6), dim3(256), 0, stream>>>(x, Wq, Wk, Wv, ws);
        attn_kernel<<<dim3(BB * CC * 4), dim3(256), 0, stream>>>(x, ws, out);
    } else {
        vn_attn_fused<<<dim3(BB * CC), dim3(256), 0, stream>>>(x, Wq, Wk, Wv, out);
    }
}

// Round 6
// 107.132 us; speedup vs baseline: 2.2363x; 2.2363x over previous
//
#include <hip/hip_runtime.h>

#define BB 8
#define CC 64
#define UU 3
#define NN 512
#define POS (UU * NN)               // 1536
#define QKV_ELEMS (BB * CC * POS)   // 786432 floats per tensor
// 0.125 (= C^-0.5) * log2(e), folded into q so softmax uses raw exp2
#define SCALE2 0.1803368801111793f

// ---------------- Kernel 1: projection (round-3 proven version) ------------
__global__ __launch_bounds__(256) void proj_kernel(
    const float* __restrict__ x,
    const float* __restrict__ Wq,
    const float* __restrict__ Wk,
    const float* __restrict__ Wv,
    float* __restrict__ ws)
{
    const int blk   = blockIdx.x;        // 0..1535
    const int bd2   = blk / 6;           // 0..255 : (b, d-pair)
    const int chunk = blk % 6;
    const int b     = bd2 >> 5;
    const int d0    = (bd2 & 31) * 2;
    const int tid   = threadIdx.x;
    const int p     = chunk * 256 + tid; // 0..1535

    __shared__ float w[6][CC];           // rows: q_d0,q_d1,k_d0,k_d1,v_d0,v_d1
    if (tid < 128) {
        int r = tid >> 6, c = tid & 63;
        w[r][c]     = Wq[(d0 + r) * CC + c];
        w[2 + r][c] = Wk[(d0 + r) * CC + c];
        w[4 + r][c] = Wv[(d0 + r) * CC + c];
    }
    __syncthreads();

    const float* xb = x + (size_t)b * CC * POS + p;
    float q0 = 0.f, q1 = 0.f, k0 = 0.f, k1 = 0.f, v0 = 0.f, v1 = 0.f;
    #pragma unroll 8
    for (int c = 0; c < CC; ++c) {
        float xv = xb[c * POS];
        q0 = fmaf(xv, w[0][c], q0);
        q1 = fmaf(xv, w[1][c], q1);
        k0 = fmaf(xv, w[2][c], k0);
        k1 = fmaf(xv, w[3][c], k1);
        v0 = fmaf(xv, w[4][c], v0);
        v1 = fmaf(xv, w[5][c], v1);
    }

    float* qs = ws;
    float* ks = ws + QKV_ELEMS;
    float* vs = ws + 2 * QKV_ELEMS;
    size_t base = (size_t)(b * CC + d0) * POS + p;
    qs[base] = q0 * SCALE2;  qs[base + POS] = q1 * SCALE2;
    ks[base] = k0;           ks[base + POS] = k1;
    vs[base] = v0;           vs[base + POS] = v1;
}

// ---------------- Kernel 2: attention, R=4 register-tiled ------------------
// Each ds_read_b128 of K/V now feeds 4 rows x 4 cols = 16 (i,j) pairs:
// LDS delivery drops from 24 B/pair (r3) to 6 B/pair -> VALU-bound.
// Lane pair (2r,2r+1): h = tid&1 selects j-half; thread owns rows
// {r, r+128, r+256, r+384}. shfl_xor(1) merges halves; LDS part[] staging
// gives fully coalesced residual+store epilogue.
__global__ __launch_bounds__(256) void attn_kernel(
    const float* __restrict__ x,
    const float* __restrict__ ws,
    float* __restrict__ out)
{
    const int bd  = blockIdx.x;    // 0..511
    const int tid = threadIdx.x;

    __shared__ __align__(16) float ks[UU][NN];
    __shared__ __align__(16) float vs[UU][NN];
    __shared__ float4 part[NN];    // (a0, a1, a2, l) per row

    const float* qsg = ws + (size_t)bd * POS;
    const float* ksg = ws + QKV_ELEMS     + (size_t)bd * POS;
    const float* vsg = ws + 2 * QKV_ELEMS + (size_t)bd * POS;

    float* ksf = &ks[0][0];
    float* vsf = &vs[0][0];
    for (int t = tid; t < POS; t += 256) {
        ksf[t] = ksg[t];
        vsf[t] = vsg[t];
    }
    __syncthreads();

    const int r = tid >> 1;        // 0..127
    const int h = tid & 1;         // j-half

    float q0[4], q1[4], q2[4];
    #pragma unroll
    for (int m = 0; m < 4; ++m) {
        int i = r + m * 128;
        q0[m] = qsg[i];            // already * C^-0.5 * log2(e)
        q1[m] = qsg[NN + i];
        q2[m] = qsg[2 * NN + i];
    }

    float l[4]  = {0.f, 0.f, 0.f, 0.f};
    float a0[4] = {0.f, 0.f, 0.f, 0.f};
    float a1[4] = {0.f, 0.f, 0.f, 0.f};
    float a2[4] = {0.f, 0.f, 0.f, 0.f};

    const float4* k0p = (const float4*)&ks[0][0] + h * 64;
    const float4* k1p = (const float4*)&ks[1][0] + h * 64;
    const float4* k2p = (const float4*)&ks[2][0] + h * 64;
    const float4* v0p = (const float4*)&vs[0][0] + h * 64;
    const float4* v1p = (const float4*)&vs[1][0] + h * 64;
    const float4* v2p = (const float4*)&vs[2][0] + h * 64;

    for (int t = 0; t < 64; ++t) {
        float4 k0 = k0p[t];
        float4 k1 = k1p[t];
        float4 k2 = k2p[t];
        float4 v0 = v0p[t];
        float4 v1 = v1p[t];
        float4 v2 = v2p[t];

        #pragma unroll
        for (int m = 0; m < 4; ++m) {
            float s0 = fmaf(q0[m], k0.x, fmaf(q1[m], k1.x, q2[m] * k2.x));
            float s1 = fmaf(q0[m], k0.y, fmaf(q1[m], k1.y, q2[m] * k2.y));
            float s2 = fmaf(q0[m], k0.z, fmaf(q1[m], k1.z, q2[m] * k2.z));
            float s3 = fmaf(q0[m], k0.w, fmaf(q1[m], k1.w, q2[m] * k2.w));

            float p0 = __builtin_amdgcn_exp2f(s0);
            float p1 = __builtin_amdgcn_exp2f(s1);
            float p2 = __builtin_amdgcn_exp2f(s2);
            float p3 = __builtin_amdgcn_exp2f(s3);

            l[m] += (p0 + p1) + (p2 + p3);
            a0[m] = fmaf(p0, v0.x, fmaf(p1, v0.y, fmaf(p2, v0.z, fmaf(p3, v0.w, a0[m]))));
            a1[m] = fmaf(p0, v1.x, fmaf(p1, v1.y, fmaf(p2, v1.z, fmaf(p3, v1.w, a1[m]))));
            a2[m] = fmaf(p0, v2.x, fmaf(p1, v2.y, fmaf(p2, v2.z, fmaf(p3, v2.w, a2[m]))));
        }
    }

    // merge the two j-halves (lane pair) and stage per-row results
    #pragma unroll
    for (int m = 0; m < 4; ++m) {
        l[m]  += __shfl_xor(l[m],  1);
        a0[m] += __shfl_xor(a0[m], 1);
        a1[m] += __shfl_xor(a1[m], 1);
        a2[m] += __shfl_xor(a2[m], 1);
    }
    if (h == 0) {
        #pragma unroll
        for (int m = 0; m < 4; ++m) {
            part[r + m * 128] = make_float4(a0[m], a1[m], a2[m], l[m]);
        }
    }
    __syncthreads();

    // coalesced epilogue: thread t finalizes rows t and t+256
    const float* xd = x   + (size_t)bd * POS;
    float*       od = out + (size_t)bd * POS;
    #pragma unroll
    for (int w = 0; w < 2; ++w) {
        int i = tid + w * 256;
        float4 P = part[i];
        float inv = 1.0f / P.w;
        od[i]          = xd[i]          + P.x * inv;
        od[NN + i]     = xd[NN + i]     + P.y * inv;
        od[2 * NN + i] = xd[2 * NN + i] + P.z * inv;
    }
}

// ---------------- Fallback: fused kernel (if ws too small) -----------------
__global__ __launch_bounds__(256) void vn_attn_fused(
    const float* __restrict__ x,
    const float* __restrict__ Wq,
    const float* __restrict__ Wk,
    const float* __restrict__ Wv,
    float* __restrict__ out)
{
    const int bd  = blockIdx.x;
    const int b   = bd / CC;
    const int d   = bd % CC;
    const int tid = threadIdx.x;

    __shared__ float wq[CC], wk[CC], wv[CC];
    __shared__ float qs[UU][NN];
    __shared__ float ks[UU][NN];
    __shared__ float vs[UU][NN];

    if (tid < CC) {
        wq[tid] = Wq[d * CC + tid];
        wk[tid] = Wk[d * CC + tid];
        wv[tid] = Wv[d * CC + tid];
    }
    __syncthreads();

    const float* xb = x + (size_t)b * CC * POS;
    for (int p = tid; p < POS; p += 256) {
        float qa = 0.f, ka = 0.f, va = 0.f;
        #pragma unroll 8
        for (int c = 0; c < CC; ++c) {
            float xv = xb[c * POS + p];
            qa = fmaf(xv, wq[c], qa);
            ka = fmaf(xv, wk[c], ka);
            va = fmaf(xv, wv[c], va);
        }
        int u = p >> 9, n = p & (NN - 1);
        qs[u][n] = qa * SCALE2;
        ks[u][n] = ka;
        vs[u][n] = va;
    }
    __syncthreads();

    for (int i = tid; i < NN; i += 256) {
        float q0 = qs[0][i], q1 = qs[1][i], q2 = qs[2][i];
        float l = 0.f, a0 = 0.f, a1 = 0.f, a2 = 0.f;
        for (int j = 0; j < NN; j += 4) {
            float4 k0 = *(const float4*)&ks[0][j];
            float4 k1 = *(const float4*)&ks[1][j];
            float4 k2 = *(const float4*)&ks[2][j];
            float4 v0 = *(const float4*)&vs[0][j];
            float4 v1 = *(const float4*)&vs[1][j];
            float4 v2 = *(const float4*)&vs[2][j];
            float s0 = fmaf(q0, k0.x, fmaf(q1, k1.x, q2 * k2.x));
            float s1 = fmaf(q0, k0.y, fmaf(q1, k1.y, q2 * k2.y));
            float s2 = fmaf(q0, k0.z, fmaf(q1, k1.z, q2 * k2.z));
            float s3 = fmaf(q0, k0.w, fmaf(q1, k1.w, q2 * k2.w));
            float p0 = __builtin_amdgcn_exp2f(s0);
            float p1 = __builtin_amdgcn_exp2f(s1);
            float p2 = __builtin_amdgcn_exp2f(s2);
            float p3 = __builtin_amdgcn_exp2f(s3);
            l += p0 + p1 + p2 + p3;
            a0 = fmaf(p0, v0.x, fmaf(p1, v0.y, fmaf(p2, v0.z, fmaf(p3, v0.w, a0))));
            a1 = fmaf(p0, v1.x, fmaf(p1, v1.y, fmaf(p2, v1.z, fmaf(p3, v1.w, a1))));
            a2 = fmaf(p0, v2.x, fmaf(p1, v2.y, fmaf(p2, v2.z, fmaf(p3, v2.w, a2))));
        }
        float inv = 1.0f / l;
        size_t obase = ((size_t)(b * CC + d) * UU) * NN + i;
        const float* xd = xb + (size_t)d * POS;
        out[obase]          = xd[i]          + a0 * inv;
        out[obase + NN]     = xd[NN + i]     + a1 * inv;
        out[obase + 2 * NN] = xd[2 * NN + i] + a2 * inv;
    }
}

extern "C" void kernel_launch(void* const* d_in, const int* in_sizes, int n_in,
                              void* d_out, int out_size, void* d_ws, size_t ws_size,
                              hipStream_t stream) {
    const float* x  = (const float*)d_in[0];
    const float* Wq = (const float*)d_in[1];
    const float* Wk = (const float*)d_in[2];
    const float* Wv = (const float*)d_in[3];
    float* out = (float*)d_out;

    if (ws_size >= (size_t)3 * QKV_ELEMS * sizeof(float)) {
        float* ws = (float*)d_ws;
        proj_kernel<<<dim3(BB * 32 * 6), dim3(256), 0, stream>>>(x, Wq, Wk, Wv, ws);
        attn_kernel<<<dim3(BB * CC), dim3(256), 0, stream>>>(x, ws, out);
    } else {
        vn_attn_fused<<<dim3(BB * CC), dim3(256), 0, stream>>>(x, Wq, Wk, Wv, out);
    }
}

// Round 7
// 105.332 us; speedup vs baseline: 2.2745x; 1.0171x over previous
//
#include <hip/hip_runtime.h>

#define BB 8
#define CC 64
#define UU 3
#define NN 512
#define POS (UU * NN)               // 1536
#define QKV_ELEMS (BB * CC * POS)   // 786432 floats per tensor
// 0.125 (= C^-0.5) * log2(e), folded into q so softmax uses raw exp2
#define SCALE2 0.1803368801111793f

// ---------------- Kernel 1: projection (round-3 proven version) ------------
__global__ __launch_bounds__(256) void proj_kernel(
    const float* __restrict__ x,
    const float* __restrict__ Wq,
    const float* __restrict__ Wk,
    const float* __restrict__ Wv,
    float* __restrict__ ws)
{
    const int blk   = blockIdx.x;        // 0..1535
    const int bd2   = blk / 6;           // 0..255 : (b, d-pair)
    const int chunk = blk % 6;
    const int b     = bd2 >> 5;
    const int d0    = (bd2 & 31) * 2;
    const int tid   = threadIdx.x;
    const int p     = chunk * 256 + tid; // 0..1535

    __shared__ float w[6][CC];           // rows: q_d0,q_d1,k_d0,k_d1,v_d0,v_d1
    if (tid < 128) {
        int r = tid >> 6, c = tid & 63;
        w[r][c]     = Wq[(d0 + r) * CC + c];
        w[2 + r][c] = Wk[(d0 + r) * CC + c];
        w[4 + r][c] = Wv[(d0 + r) * CC + c];
    }
    __syncthreads();

    const float* xb = x + (size_t)b * CC * POS + p;
    float q0 = 0.f, q1 = 0.f, k0 = 0.f, k1 = 0.f, v0 = 0.f, v1 = 0.f;
    #pragma unroll 8
    for (int c = 0; c < CC; ++c) {
        float xv = xb[c * POS];
        q0 = fmaf(xv, w[0][c], q0);
        q1 = fmaf(xv, w[1][c], q1);
        k0 = fmaf(xv, w[2][c], k0);
        k1 = fmaf(xv, w[3][c], k1);
        v0 = fmaf(xv, w[4][c], v0);
        v1 = fmaf(xv, w[5][c], v1);
    }

    float* qs = ws;
    float* ks = ws + QKV_ELEMS;
    float* vs = ws + 2 * QKV_ELEMS;
    size_t base = (size_t)(b * CC + d0) * POS + p;
    qs[base] = q0 * SCALE2;  qs[base + POS] = q1 * SCALE2;
    ks[base] = k0;           ks[base + POS] = k1;
    vs[base] = v0;           vs[base + POS] = v1;
}

// ---------------- Kernel 2: attention, R=4 tiled, 4-way j-split ------------
// grid = 512 bd x 2 row-halves = 1024 blocks (4 blocks/CU -> 4 waves/SIMD).
// h = tid&3 selects a 128-wide j-quarter; slot = tid>>2 ; thread owns rows
// {slot, slot+64, slot+128, slot+192} of its half. Each 6x ds_read_b128
// serves 4 rows x 4 j = 16 pairs (6 B/pair). Quarter bases alias banks
// (512 B apart), so iterate t = (tt + 2h) & 31: the 4 addresses per read
// instr then occupy disjoint bank-quads (conflict-free). 2-step shfl_xor
// butterfly merges the 4 j-quarters (lanes 4s..4s+3 are wave-contiguous).
__global__ __launch_bounds__(256) void attn_kernel(
    const float* __restrict__ x,
    const float* __restrict__ ws,
    float* __restrict__ out)
{
    const int blk  = blockIdx.x;   // 0..1023
    const int bd   = blk >> 1;     // 0..511
    const int half = blk & 1;
    const int tid  = threadIdx.x;

    __shared__ __align__(16) float ks[UU][NN];
    __shared__ __align__(16) float vs[UU][NN];
    __shared__ float4 part[NN / 2];    // (a0, a1, a2, l) per block-local row

    const float* qsg = ws + (size_t)bd * POS;
    const float* ksg = ws + QKV_ELEMS     + (size_t)bd * POS;
    const float* vsg = ws + 2 * QKV_ELEMS + (size_t)bd * POS;

    // stage K and V (6 KB each, contiguous) as float4
    {
        const float4* kg4 = (const float4*)ksg;
        const float4* vg4 = (const float4*)vsg;
        float4* ks4 = (float4*)&ks[0][0];
        float4* vs4 = (float4*)&vs[0][0];
        #pragma unroll
        for (int it = 0; it < 3; ++it) {
            int idx = tid + it * 256;        // 0..767
            if (idx < 384) ks4[idx] = kg4[idx];
            else           vs4[idx - 384] = vg4[idx - 384];
        }
    }
    __syncthreads();

    const int h    = tid & 3;      // j-quarter
    const int slot = tid >> 2;     // 0..63

    float q0[4], q1[4], q2[4];
    #pragma unroll
    for (int m = 0; m < 4; ++m) {
        int i = half * 256 + slot + m * 64;
        q0[m] = qsg[i];            // already * C^-0.5 * log2(e)
        q1[m] = qsg[NN + i];
        q2[m] = qsg[2 * NN + i];
    }

    float l[4]  = {0.f, 0.f, 0.f, 0.f};
    float a0[4] = {0.f, 0.f, 0.f, 0.f};
    float a1[4] = {0.f, 0.f, 0.f, 0.f};
    float a2[4] = {0.f, 0.f, 0.f, 0.f};

    const float4* k0p = (const float4*)&ks[0][0] + h * 32;
    const float4* k1p = (const float4*)&ks[1][0] + h * 32;
    const float4* k2p = (const float4*)&ks[2][0] + h * 32;
    const float4* v0p = (const float4*)&vs[0][0] + h * 32;
    const float4* v1p = (const float4*)&vs[1][0] + h * 32;
    const float4* v2p = (const float4*)&vs[2][0] + h * 32;
    const int t0 = 2 * h;          // bank-stagger offset

    #pragma unroll 2
    for (int tt = 0; tt < 32; ++tt) {
        const int t = (tt + t0) & 31;
        float4 k0 = k0p[t];
        float4 k1 = k1p[t];
        float4 k2 = k2p[t];
        float4 v0 = v0p[t];
        float4 v1 = v1p[t];
        float4 v2 = v2p[t];

        #pragma unroll
        for (int m = 0; m < 4; ++m) {
            float s0 = fmaf(q0[m], k0.x, fmaf(q1[m], k1.x, q2[m] * k2.x));
            float s1 = fmaf(q0[m], k0.y, fmaf(q1[m], k1.y, q2[m] * k2.y));
            float s2 = fmaf(q0[m], k0.z, fmaf(q1[m], k1.z, q2[m] * k2.z));
            float s3 = fmaf(q0[m], k0.w, fmaf(q1[m], k1.w, q2[m] * k2.w));

            float p0 = __builtin_amdgcn_exp2f(s0);
            float p1 = __builtin_amdgcn_exp2f(s1);
            float p2 = __builtin_amdgcn_exp2f(s2);
            float p3 = __builtin_amdgcn_exp2f(s3);

            l[m] += (p0 + p1) + (p2 + p3);
            a0[m] = fmaf(p0, v0.x, fmaf(p1, v0.y, fmaf(p2, v0.z, fmaf(p3, v0.w, a0[m]))));
            a1[m] = fmaf(p0, v1.x, fmaf(p1, v1.y, fmaf(p2, v1.z, fmaf(p3, v1.w, a1[m]))));
            a2[m] = fmaf(p0, v2.x, fmaf(p1, v2.y, fmaf(p2, v2.z, fmaf(p3, v2.w, a2[m]))));
        }
    }

    // merge the 4 j-quarters (4-lane butterfly) and stage per-row results
    #pragma unroll
    for (int m = 0; m < 4; ++m) {
        l[m]  += __shfl_xor(l[m],  1);  l[m]  += __shfl_xor(l[m],  2);
        a0[m] += __shfl_xor(a0[m], 1);  a0[m] += __shfl_xor(a0[m], 2);
        a1[m] += __shfl_xor(a1[m], 1);  a1[m] += __shfl_xor(a1[m], 2);
        a2[m] += __shfl_xor(a2[m], 1);  a2[m] += __shfl_xor(a2[m], 2);
    }
    if (h == 0) {
        #pragma unroll
        for (int m = 0; m < 4; ++m) {
            part[slot + m * 64] = make_float4(a0[m], a1[m], a2[m], l[m]);
        }
    }
    __syncthreads();

    // coalesced epilogue: thread t finalizes block-local row t
    const int i = half * 256 + tid;
    float4 P = part[tid];
    float inv = 1.0f / P.w;
    const float* xd = x   + (size_t)bd * POS;
    float*       od = out + (size_t)bd * POS;
    od[i]          = xd[i]          + P.x * inv;
    od[NN + i]     = xd[NN + i]     + P.y * inv;
    od[2 * NN + i] = xd[2 * NN + i] + P.z * inv;
}

// ---------------- Fallback: fused kernel (if ws too small) -----------------
__global__ __launch_bounds__(256) void vn_attn_fused(
    const float* __restrict__ x,
    const float* __restrict__ Wq,
    const float* __restrict__ Wk,
    const float* __restrict__ Wv,
    float* __restrict__ out)
{
    const int bd  = blockIdx.x;
    const int b   = bd / CC;
    const int d   = bd % CC;
    const int tid = threadIdx.x;

    __shared__ float wq[CC], wk[CC], wv[CC];
    __shared__ float qs[UU][NN];
    __shared__ float ks[UU][NN];
    __shared__ float vs[UU][NN];

    if (tid < CC) {
        wq[tid] = Wq[d * CC + tid];
        wk[tid] = Wk[d * CC + tid];
        wv[tid] = Wv[d * CC + tid];
    }
    __syncthreads();

    const float* xb = x + (size_t)b * CC * POS;
    for (int p = tid; p < POS; p += 256) {
        float qa = 0.f, ka = 0.f, va = 0.f;
        #pragma unroll 8
        for (int c = 0; c < CC; ++c) {
            float xv = xb[c * POS + p];
            qa = fmaf(xv, wq[c], qa);
            ka = fmaf(xv, wk[c], ka);
            va = fmaf(xv, wv[c], va);
        }
        int u = p >> 9, n = p & (NN - 1);
        qs[u][n] = qa * SCALE2;
        ks[u][n] = ka;
        vs[u][n] = va;
    }
    __syncthreads();

    for (int i = tid; i < NN; i += 256) {
        float q0 = qs[0][i], q1 = qs[1][i], q2 = qs[2][i];
        float l = 0.f, a0 = 0.f, a1 = 0.f, a2 = 0.f;
        for (int j = 0; j < NN; j += 4) {
            float4 k0 = *(const float4*)&ks[0][j];
            float4 k1 = *(const float4*)&ks[1][j];
            float4 k2 = *(const float4*)&ks[2][j];
            float4 v0 = *(const float4*)&vs[0][j];
            float4 v1 = *(const float4*)&vs[1][j];
            float4 v2 = *(const float4*)&vs[2][j];
            float s0 = fmaf(q0, k0.x, fmaf(q1, k1.x, q2 * k2.x));
            float s1 = fmaf(q0, k0.y, fmaf(q1, k1.y, q2 * k2.y));
            float s2 = fmaf(q0, k0.z, fmaf(q1, k1.z, q2 * k2.z));
            float s3 = fmaf(q0, k0.w, fmaf(q1, k1.w, q2 * k2.w));
            float p0 = __builtin_amdgcn_exp2f(s0);
            float p1 = __builtin_amdgcn_exp2f(s1);
            float p2 = __builtin_amdgcn_exp2f(s2);
            float p3 = __builtin_amdgcn_exp2f(s3);
            l += p0 + p1 + p2 + p3;
            a0 = fmaf(p0, v0.x, fmaf(p1, v0.y, fmaf(p2, v0.z, fmaf(p3, v0.w, a0))));
            a1 = fmaf(p0, v1.x, fmaf(p1, v1.y, fmaf(p2, v1.z, fmaf(p3, v1.w, a1))));
            a2 = fmaf(p0, v2.x, fmaf(p1, v2.y, fmaf(p2, v2.z, fmaf(p3, v2.w, a2))));
        }
        float inv = 1.0f / l;
        size_t obase = ((size_t)(b * CC + d) * UU) * NN + i;
        const float* xd = xb + (size_t)d * POS;
        out[obase]          = xd[i]          + a0 * inv;
        out[obase + NN]     = xd[NN + i]     + a1 * inv;
        out[obase + 2 * NN] = xd[2 * NN + i] + a2 * inv;
    }
}

extern "C" void kernel_launch(void* const* d_in, const int* in_sizes, int n_in,
                              void* d_out, int out_size, void* d_ws, size_t ws_size,
                              hipStream_t stream) {
    const float* x  = (const float*)d_in[0];
    const float* Wq = (const float*)d_in[1];
    const float* Wk = (const float*)d_in[2];
    const float* Wv = (const float*)d_in[3];
    float* out = (float*)d_out;

    if (ws_size >= (size_t)3 * QKV_ELEMS * sizeof(float)) {
        float* ws = (float*)d_ws;
        proj_kernel<<<dim3(BB * 32 * 6), dim3(256), 0, stream>>>(x, Wq, Wk, Wv, ws);
        attn_kernel<<<dim3(BB * CC * 2), dim3(256), 0, stream>>>(x, ws, out);
    } else {
        vn_attn_fused<<<dim3(BB * CC), dim3(256), 0, stream>>>(x, Wq, Wk, Wv, out);
    }
}

// Round 11
// 98.392 us; speedup vs baseline: 2.4350x; 1.0705x over previous
//
#include <hip/hip_runtime.h>

#define BB 8
#define CC 64
#define UU 3
#define NN 512
#define POS (UU * NN)               // 1536
#define QKV_ELEMS (BB * CC * POS)   // 786432 floats per tensor
// 0.125 (= C^-0.5) * log2(e), folded into q so softmax uses raw exp2
#define SCALE2 0.1803368801111793f

typedef float f2 __attribute__((ext_vector_type(2)));

// ---------------- Kernel 1: projection, DD=4, W via scalar loads -----------
// Block = (b, d-quad, 256-position chunk); d-quad derived from blockIdx ONLY,
// so W addresses are block-uniform -> s_load (scalar pipe, no LDS, no VMEM).
// x over-read drops 32x -> 16x (100 MB through L2/L3). grid = 8*16*6 = 768
// blocks = 3 blocks/CU. Per thread: 12 accumulators, per c: 1 x load + 12 FMA.
__global__ __launch_bounds__(256) void proj_kernel(
    const float* __restrict__ x,
    const float* __restrict__ Wq,
    const float* __restrict__ Wk,
    const float* __restrict__ Wv,
    float* __restrict__ ws)
{
    const int blk   = blockIdx.x;        // 0..767
    const int bq    = blk / 6;           // 0..127 : (b, d-quad)
    const int chunk = blk % 6;
    const int b     = bq >> 4;
    const int d0    = (bq & 15) * 4;
    const int p     = chunk * 256 + threadIdx.x;   // 0..1535

    const float* wq = Wq + (size_t)d0 * CC;   // block-uniform rows
    const float* wk = Wk + (size_t)d0 * CC;
    const float* wv = Wv + (size_t)d0 * CC;
    const float* xb = x + (size_t)b * CC * POS + p;

    float qa[4] = {0.f, 0.f, 0.f, 0.f};
    float ka[4] = {0.f, 0.f, 0.f, 0.f};
    float va[4] = {0.f, 0.f, 0.f, 0.f};

    #pragma unroll 4
    for (int c = 0; c < CC; ++c) {
        float xv = xb[c * POS];
        #pragma unroll
        for (int r = 0; r < 4; ++r) {
            qa[r] = fmaf(xv, wq[r * CC + c], qa[r]);   // uniform -> s_load
            ka[r] = fmaf(xv, wk[r * CC + c], ka[r]);
            va[r] = fmaf(xv, wv[r * CC + c], va[r]);
        }
    }

    float* qs = ws;
    float* ks = ws + QKV_ELEMS;
    float* vs = ws + 2 * QKV_ELEMS;
    #pragma unroll
    for (int r = 0; r < 4; ++r) {
        size_t base = (size_t)(b * CC + d0 + r) * POS + p;
        qs[base] = qa[r] * SCALE2;
        ks[base] = ka[r];
        vs[base] = va[r];
    }
}

// ---------------- Kernel 2: attention, R=4 tiled, packed-fp32 math ---------
// Same structure as r7 (grid 1024, 4-way j-split, bank-staggered b128 reads),
// but the inner math runs on float2 ext-vectors -> v_pk_fma_f32 (VOP3P,
// 2 FMA per issue) halving VALU issue count: 240 vs 352 cyc per m-iter.
__global__ __launch_bounds__(256, 4) void attn_kernel(
    const float* __restrict__ x,
    const float* __restrict__ ws,
    float* __restrict__ out)
{
    const int blk  = blockIdx.x;   // 0..1023
    const int bd   = blk >> 1;     // 0..511
    const int half = blk & 1;
    const int tid  = threadIdx.x;

    __shared__ __align__(16) float ks[UU][NN];
    __shared__ __align__(16) float vs[UU][NN];
    __shared__ float4 part[NN / 2];    // (a0, a1, a2, l) per block-local row

    const float* qsg = ws + (size_t)bd * POS;
    const float* ksg = ws + QKV_ELEMS     + (size_t)bd * POS;
    const float* vsg = ws + 2 * QKV_ELEMS + (size_t)bd * POS;

    // stage K and V (6 KB each, contiguous) as float4
    {
        const float4* kg4 = (const float4*)ksg;
        const float4* vg4 = (const float4*)vsg;
        float4* ks4 = (float4*)&ks[0][0];
        float4* vs4 = (float4*)&vs[0][0];
        #pragma unroll
        for (int it = 0; it < 3; ++it) {
            int idx = tid + it * 256;        // 0..767
            if (idx < 384) ks4[idx] = kg4[idx];
            else           vs4[idx - 384] = vg4[idx - 384];
        }
    }
    __syncthreads();

    const int h    = tid & 3;      // j-quarter
    const int slot = tid >> 2;     // 0..63

    f2 Q0[4], Q1[4], Q2[4];
    #pragma unroll
    for (int m = 0; m < 4; ++m) {
        int i = half * 256 + slot + m * 64;
        float a = qsg[i], b = qsg[NN + i], c = qsg[2 * NN + i];
        Q0[m] = (f2){a, a};
        Q1[m] = (f2){b, b};
        Q2[m] = (f2){c, c};
    }

    f2 L[4], A0[4], A1[4], A2[4];
    #pragma unroll
    for (int m = 0; m < 4; ++m) {
        L[m] = (f2){0.f, 0.f};  A0[m] = (f2){0.f, 0.f};
        A1[m] = (f2){0.f, 0.f}; A2[m] = (f2){0.f, 0.f};
    }

    const float4* k0p = (const float4*)&ks[0][0] + h * 32;
    const float4* k1p = (const float4*)&ks[1][0] + h * 32;
    const float4* k2p = (const float4*)&ks[2][0] + h * 32;
    const float4* v0p = (const float4*)&vs[0][0] + h * 32;
    const float4* v1p = (const float4*)&vs[1][0] + h * 32;
    const float4* v2p = (const float4*)&vs[2][0] + h * 32;
    const int t0 = 2 * h;          // bank-stagger offset

    #pragma unroll 2
    for (int tt = 0; tt < 32; ++tt) {
        const int t = (tt + t0) & 31;
        float4 k0 = k0p[t];
        float4 k1 = k1p[t];
        float4 k2 = k2p[t];
        float4 v0 = v0p[t];
        float4 v1 = v1p[t];
        float4 v2 = v2p[t];

        f2 k0a = (f2){k0.x, k0.y}, k0b = (f2){k0.z, k0.w};
        f2 k1a = (f2){k1.x, k1.y}, k1b = (f2){k1.z, k1.w};
        f2 k2a = (f2){k2.x, k2.y}, k2b = (f2){k2.z, k2.w};
        f2 v0a = (f2){v0.x, v0.y}, v0b = (f2){v0.z, v0.w};
        f2 v1a = (f2){v1.x, v1.y}, v1b = (f2){v1.z, v1.w};
        f2 v2a = (f2){v2.x, v2.y}, v2b = (f2){v2.z, v2.w};

        #pragma unroll
        for (int m = 0; m < 4; ++m) {
            f2 sa = __builtin_elementwise_fma(Q0[m], k0a,
                     __builtin_elementwise_fma(Q1[m], k1a, Q2[m] * k2a));
            f2 sb = __builtin_elementwise_fma(Q0[m], k0b,
                     __builtin_elementwise_fma(Q1[m], k1b, Q2[m] * k2b));

            f2 pa = (f2){__builtin_amdgcn_exp2f(sa.x), __builtin_amdgcn_exp2f(sa.y)};
            f2 pb = (f2){__builtin_amdgcn_exp2f(sb.x), __builtin_amdgcn_exp2f(sb.y)};

            L[m]  = L[m] + pa + pb;
            A0[m] = __builtin_elementwise_fma(pa, v0a,
                      __builtin_elementwise_fma(pb, v0b, A0[m]));
            A1[m] = __builtin_elementwise_fma(pa, v1a,
                      __builtin_elementwise_fma(pb, v1b, A1[m]));
            A2[m] = __builtin_elementwise_fma(pa, v2a,
                      __builtin_elementwise_fma(pb, v2b, A2[m]));
        }
    }

    // collapse packed halves, merge the 4 j-quarters (4-lane butterfly)
    #pragma unroll
    for (int m = 0; m < 4; ++m) {
        float l  = L[m].x  + L[m].y;
        float a0 = A0[m].x + A0[m].y;
        float a1 = A1[m].x + A1[m].y;
        float a2 = A2[m].x + A2[m].y;

        l  += __shfl_xor(l,  1);  l  += __shfl_xor(l,  2);
        a0 += __shfl_xor(a0, 1);  a0 += __shfl_xor(a0, 2);
        a1 += __shfl_xor(a1, 1);  a1 += __shfl_xor(a1, 2);
        a2 += __shfl_xor(a2, 1);  a2 += __shfl_xor(a2, 2);

        if (h == 0) part[slot + m * 64] = make_float4(a0, a1, a2, l);
    }
    __syncthreads();

    // coalesced epilogue: thread t finalizes block-local row t
    const int i = half * 256 + tid;
    float4 P = part[tid];
    float inv = 1.0f / P.w;
    const float* xd = x   + (size_t)bd * POS;
    float*       od = out + (size_t)bd * POS;
    od[i]          = xd[i]          + P.x * inv;
    od[NN + i]     = xd[NN + i]     + P.y * inv;
    od[2 * NN + i] = xd[2 * NN + i] + P.z * inv;
}

// ---------------- Fallback: fused kernel (if ws too small) -----------------
__global__ __launch_bounds__(256) void vn_attn_fused(
    const float* __restrict__ x,
    const float* __restrict__ Wq,
    const float* __restrict__ Wk,
    const float* __restrict__ Wv,
    float* __restrict__ out)
{
    const int bd  = blockIdx.x;
    const int b   = bd / CC;
    const int d   = bd % CC;
    const int tid = threadIdx.x;

    __shared__ float wq[CC], wk[CC], wv[CC];
    __shared__ float qs[UU][NN];
    __shared__ float ks[UU][NN];
    __shared__ float vs[UU][NN];

    if (tid < CC) {
        wq[tid] = Wq[d * CC + tid];
        wk[tid] = Wk[d * CC + tid];
        wv[tid] = Wv[d * CC + tid];
    }
    __syncthreads();

    const float* xb = x + (size_t)b * CC * POS;
    for (int p = tid; p < POS; p += 256) {
        float qa = 0.f, ka = 0.f, va = 0.f;
        #pragma unroll 8
        for (int c = 0; c < CC; ++c) {
            float xv = xb[c * POS + p];
            qa = fmaf(xv, wq[c], qa);
            ka = fmaf(xv, wk[c], ka);
            va = fmaf(xv, wv[c], va);
        }
        int u = p >> 9, n = p & (NN - 1);
        qs[u][n] = qa * SCALE2;
        ks[u][n] = ka;
        vs[u][n] = va;
    }
    __syncthreads();

    for (int i = tid; i < NN; i += 256) {
        float q0 = qs[0][i], q1 = qs[1][i], q2 = qs[2][i];
        float l = 0.f, a0 = 0.f, a1 = 0.f, a2 = 0.f;
        for (int j = 0; j < NN; j += 4) {
            float4 k0 = *(const float4*)&ks[0][j];
            float4 k1 = *(const float4*)&ks[1][j];
            float4 k2 = *(const float4*)&ks[2][j];
            float4 v0 = *(const float4*)&vs[0][j];
            float4 v1 = *(const float4*)&vs[1][j];
            float4 v2 = *(const float4*)&vs[2][j];
            float s0 = fmaf(q0, k0.x, fmaf(q1, k1.x, q2 * k2.x));
            float s1 = fmaf(q0, k0.y, fmaf(q1, k1.y, q2 * k2.y));
            float s2 = fmaf(q0, k0.z, fmaf(q1, k1.z, q2 * k2.z));
            float s3 = fmaf(q0, k0.w, fmaf(q1, k1.w, q2 * k2.w));
            float p0 = __builtin_amdgcn_exp2f(s0);
            float p1 = __builtin_amdgcn_exp2f(s1);
            float p2 = __builtin_amdgcn_exp2f(s2);
            float p3 = __builtin_amdgcn_exp2f(s3);
            l += p0 + p1 + p2 + p3;
            a0 = fmaf(p0, v0.x, fmaf(p1, v0.y, fmaf(p2, v0.z, fmaf(p3, v0.w, a0))));
            a1 = fmaf(p0, v1.x, fmaf(p1, v1.y, fmaf(p2, v1.z, fmaf(p3, v1.w, a1))));
            a2 = fmaf(p0, v2.x, fmaf(p1, v2.y, fmaf(p2, v2.z, fmaf(p3, v2.w, a2))));
        }
        float inv = 1.0f / l;
        size_t obase = ((size_t)(b * CC + d) * UU) * NN + i;
        const float* xd = xb + (size_t)d * POS;
        out[obase]          = xd[i]          + a0 * inv;
        out[obase + NN]     = xd[NN + i]     + a1 * inv;
        out[obase + 2 * NN] = xd[2 * NN + i] + a2 * inv;
    }
}

extern "C" void kernel_launch(void* const* d_in, const int* in_sizes, int n_in,
                              void* d_out, int out_size, void* d_ws, size_t ws_size,
                              hipStream_t stream) {
    const float* x  = (const float*)d_in[0];
    const float* Wq = (const float*)d_in[1];
    const float* Wk = (const float*)d_in[2];
    const float* Wv = (const float*)d_in[3];
    float* out = (float*)d_out;

    if (ws_size >= (size_t)3 * QKV_ELEMS * sizeof(float)) {
        float* ws = (float*)d_ws;
        proj_kernel<<<dim3(8 * 16 * 6), dim3(256), 0, stream>>>(x, Wq, Wk, Wv, ws);
        attn_kernel<<<dim3(BB * CC * 2), dim3(256), 0, stream>>>(x, ws, out);
    } else {
        vn_attn_fused<<<dim3(BB * CC), dim3(256), 0, stream>>>(x, Wq, Wk, Wv, out);
    }
}